// Round 2
// baseline (6690.312 us; speedup 1.0000x reference)
//
#include <hip/hip_runtime.h>
#include <cstdint>
#include <cstddef>

#define Hn 256
#define Sn 2048
#define Bn 128
#define NT 1024

typedef _Float16 half2_t __attribute__((ext_vector_type(2)));

__device__ __forceinline__ float fdot2_(half2_t a, half2_t b, float c){
#if __has_builtin(__builtin_amdgcn_fdot2)
  return __builtin_amdgcn_fdot2(a, b, c, false);
#else
  float d;
  asm volatile("v_dot2_f32_f16 %0, %1, %2, %3" : "=v"(d) : "v"(a), "v"(b), "v"(c));
  return d;
#endif
}

// sum over the 4 lanes of each quad (lanes l, l^1, l^2, l^3) via DPP quad_perm
__device__ __forceinline__ float qsum_(float v){
  int x = __builtin_bit_cast(int, v);
  int y = __builtin_amdgcn_mov_dpp(x, 0xB1, 0xF, 0xF, true);   // quad_perm [1,0,3,2]
  v += __builtin_bit_cast(float, y);
  x = __builtin_bit_cast(int, v);
  y = __builtin_amdgcn_mov_dpp(x, 0x4E, 0xF, 0xF, true);       // quad_perm [2,3,0,1]
  return v + __builtin_bit_cast(float, y);
}

__device__ __forceinline__ float sigmoid_(float v){ return 1.0f/(1.0f+__expf(-v)); }
__device__ __forceinline__ float tanh_(float v){
  float e = __expf(-2.0f*__builtin_fabsf(v));
  float r = (1.0f-e)/(1.0f+e);
  return __builtin_copysignf(r, v);
}

// One workgroup (1024 thr) per batch element. Thread t: j = t>>2 (h-index),
// kq = t&3 (K-quarter). Owns K-chunk [64kq,64kq+64) of w_hh rows {j, j+256, j+512}
// (r/z/n gates of h-index j): 96 f16-pair VGPRs. Quad-DPP combines K-partials.
__global__ void __launch_bounds__(NT, 4)
bio_rnn(const float* __restrict__ x,
        const float* __restrict__ w_ih, const float* __restrict__ w_hh,
        const float* __restrict__ b_ih, const float* __restrict__ b_hh,
        const float* __restrict__ w_gain, const float* __restrict__ b_gain,
        const float* __restrict__ w_bias, const float* __restrict__ b_bias,
        const float* __restrict__ w_reflex, const float* __restrict__ b_reflex,
        const float* __restrict__ w_policy, const float* __restrict__ b_policy,
        const float* __restrict__ w_motor, const float* __restrict__ b_motor,
        float* __restrict__ y_out, float* __restrict__ router)
{
  const int b  = blockIdx.x;
  const int t  = threadIdx.x;
  const int kq = t & 3;
  const int j  = t >> 2;

  // h packed f16; 4 chunks of 64 halves, padded to 160 B stride (16B-aligned,
  // conflict-free for the per-quad 4-address read pattern)
  __shared__ __align__(16) unsigned char hraw[4*160];
  __shared__ float PRE[4][Hn];          // pre-activations: r, z, gh_n, gi_n
  __shared__ float REDp[4][8];          // gain/bias head wave-partials
  __shared__ float REDq[4][4];          // policy/motor head wave-partials
  __shared__ float HW[13][Hn];          // head weights

  // ---- register-cache w_hh: 3 rows x 32 half2 = 96 VGPRs ----
  half2_t w0[32], w1[32], w2[32];
  {
    const float* p0 = w_hh + (size_t)(j       )*Hn + kq*64;
    const float* p1 = w_hh + (size_t)(j +   Hn)*Hn + kq*64;
    const float* p2 = w_hh + (size_t)(j + 2*Hn)*Hn + kq*64;
    #pragma unroll
    for (int m = 0; m < 32; m++){
      half2_t a; a.x=(_Float16)p0[2*m]; a.y=(_Float16)p0[2*m+1]; w0[m]=a;
      half2_t c; c.x=(_Float16)p1[2*m]; c.y=(_Float16)p1[2*m+1]; w1[m]=c;
      half2_t d; d.x=(_Float16)p2[2*m]; d.y=(_Float16)p2[2*m+1]; w2[m]=d;
    }
  }
  // gi fold: kq 0/1/2 handle x-dims {2kq,2kq+1}; kq==3 carries the biases.
  // n-gate keeps gi separate (n = tanh(gi_n + r*gh_n)): acc3 = gi_n partials.
  half2_t wi0, wi1, wi2; float bd0, bd1, bd2, bd3;
  {
    half2_t z; z.x=(_Float16)0.f; z.y=(_Float16)0.f;
    wi0=z; wi1=z; wi2=z; bd0=bd1=bd2=bd3=0.f;
    if (kq < 3){
      wi0.x=(_Float16)w_ih[(size_t)(j       )*6+2*kq]; wi0.y=(_Float16)w_ih[(size_t)(j       )*6+2*kq+1];
      wi1.x=(_Float16)w_ih[(size_t)(j +   Hn)*6+2*kq]; wi1.y=(_Float16)w_ih[(size_t)(j +   Hn)*6+2*kq+1];
      wi2.x=(_Float16)w_ih[(size_t)(j + 2*Hn)*6+2*kq]; wi2.y=(_Float16)w_ih[(size_t)(j + 2*Hn)*6+2*kq+1];
    } else {
      bd0 = b_ih[j]      + b_hh[j];
      bd1 = b_ih[j+Hn]   + b_hh[j+Hn];
      bd2 = b_hh[j+2*Hn];                 // gh_n bias (inside r*gh_n)
      bd3 = b_ih[j+2*Hn];                 // gi_n bias
    }
  }
  if (t < Hn){
    HW[0][t] = w_gain[t];        HW[1][t]  = w_gain[Hn + t];
    HW[2][t] = w_bias[t];        HW[3][t]  = w_bias[Hn + t];
    HW[4][t] = w_bias[2*Hn + t]; HW[5][t]  = w_bias[3*Hn + t];
    HW[6][t] = w_reflex[2*t];    HW[7][t]  = w_reflex[2*t + 1];
    HW[8][t] = b_reflex[t];
    HW[9][t] = w_policy[t];      HW[10][t] = w_policy[Hn + t];
    HW[11][t] = w_motor[t];      HW[12][t] = w_motor[Hn + t];
  }
  if (t < 160) ((unsigned int*)hraw)[t] = 0u;
  float hprev = 0.f;
  // block-uniform scalars
  const float sbg0=b_gain[0], sbg1=b_gain[1];
  const float sbb0=b_bias[0], sbb1=b_bias[1], sbb2=b_bias[2], sbb3=b_bias[3];
  const float sbp0=b_policy[0], sbp1=b_policy[1], sbm0=b_motor[0], sbm1=b_motor[1];
  __syncthreads();

  const float* xp   = x      + (size_t)b * Sn * 6;
  float* rbase      = router + (size_t)b * Sn * Hn;
  float* yo         = y_out  + (size_t)b * Sn * 4;
  const uint4* hc   = (const uint4*)(hraw + kq*160);

  for (int s = 0; s < Sn; s++){
    const float x0=xp[0], x1=xp[1], x2=xp[2], x3=xp[3], x4=xp[4], x5=xp[5];
    // this thread's x-pair (kq==3: operands are zero so value is irrelevant)
    float xa = (kq==0)?x0:((kq==1)?x2:x4);
    float xb = (kq==0)?x1:((kq==1)?x3:x5);
    half2_t xpk; xpk.x=(_Float16)xa; xpk.y=(_Float16)xb;

    float a0=bd0, a1=bd1, a2=bd2, a3=bd3;
    a0 = fdot2_(wi0, xpk, a0);      // gi fold for r row
    a1 = fdot2_(wi1, xpk, a1);      // gi fold for z row
    a3 = fdot2_(wi2, xpk, a3);      // gi_n partial (kept separate from gh_n)

    #pragma unroll
    for (int i = 0; i < 8; i++){
      uint4 hv = hc[i];             // ds_read_b128, broadcast within 16-lane groups
      half2_t h0 = __builtin_bit_cast(half2_t, hv.x);
      half2_t h1 = __builtin_bit_cast(half2_t, hv.y);
      half2_t h2 = __builtin_bit_cast(half2_t, hv.z);
      half2_t h3 = __builtin_bit_cast(half2_t, hv.w);
      a0=fdot2_(w0[4*i+0],h0,a0); a1=fdot2_(w1[4*i+0],h0,a1); a2=fdot2_(w2[4*i+0],h0,a2);
      a0=fdot2_(w0[4*i+1],h1,a0); a1=fdot2_(w1[4*i+1],h1,a1); a2=fdot2_(w2[4*i+1],h1,a2);
      a0=fdot2_(w0[4*i+2],h2,a0); a1=fdot2_(w1[4*i+2],h2,a1); a2=fdot2_(w2[4*i+2],h2,a2);
      a0=fdot2_(w0[4*i+3],h3,a0); a1=fdot2_(w1[4*i+3],h3,a1); a2=fdot2_(w2[4*i+3],h3,a2);
    }
    // combine the 4 K-partials within each quad (pure VALU)
    a0 = qsum_(a0); a1 = qsum_(a1); a2 = qsum_(a2); a3 = qsum_(a3);
    if (kq == 0){ PRE[0][j]=a0; PRE[1][j]=a1; PRE[2][j]=a2; PRE[3][j]=a3; }
    __syncthreads();                                        // W1

    if (t < Hn){
      float pr = PRE[0][t], pz = PRE[1][t], pg = PRE[2][t], pn = PRE[3][t];
      float r = sigmoid_(pr);
      float z = sigmoid_(pz);
      float n = tanh_(pn + r*pg);
      float h = (1.f - z)*n + z*hprev;
      hprev = h;
      *(_Float16*)(hraw + (t>>6)*160 + (t&63)*2) = (_Float16)h;
      rbase[(size_t)s*Hn + t] = h;                          // router_activity
      float p0=h*HW[0][t], p1=h*HW[1][t], p2=h*HW[2][t];
      float p3=h*HW[3][t], p4=h*HW[4][t], p5=h*HW[5][t];
      #pragma unroll
      for (int off = 32; off >= 1; off >>= 1){
        p0 += __shfl_xor(p0, off); p1 += __shfl_xor(p1, off); p2 += __shfl_xor(p2, off);
        p3 += __shfl_xor(p3, off); p4 += __shfl_xor(p4, off); p5 += __shfl_xor(p5, off);
      }
      if ((t & 63) == 0){
        const int wv = t >> 6;
        REDp[wv][0]=p0; REDp[wv][1]=p1; REDp[wv][2]=p2;
        REDp[wv][3]=p3; REDp[wv][4]=p4; REDp[wv][5]=p5;
      }
    }
    __syncthreads();                                        // W2
    if (t < Hn){
      // every thread redundantly combines the 4 wave-partials (broadcast reads)
      float g0 = REDp[0][0]+REDp[1][0]+REDp[2][0]+REDp[3][0] + sbg0;
      float g1 = REDp[0][1]+REDp[1][1]+REDp[2][1]+REDp[3][1] + sbg1;
      g0 = sigmoid_(g0); g1 = sigmoid_(g1);
      float f = (x0*g0)*HW[6][t] + (x1*g1)*HW[7][t] + HW[8][t];
      f = fmaxf(f, 0.f);                                    // feat
      float q0=f*HW[9][t], q1=f*HW[10][t], q2=f*HW[11][t], q3=f*HW[12][t];
      #pragma unroll
      for (int off = 32; off >= 1; off >>= 1){
        q0 += __shfl_xor(q0, off); q1 += __shfl_xor(q1, off);
        q2 += __shfl_xor(q2, off); q3 += __shfl_xor(q3, off);
      }
      if ((t & 63) == 0){
        const int wv = t >> 6;
        REDq[wv][0]=q0; REDq[wv][1]=q1; REDq[wv][2]=q2; REDq[wv][3]=q3;
      }
    }
    __syncthreads();                                        // W3
    if (t == 0){
      float s0 = REDq[0][0]+REDq[1][0]+REDq[2][0]+REDq[3][0];
      float s1 = REDq[0][1]+REDq[1][1]+REDq[2][1]+REDq[3][1];
      float s2 = REDq[0][2]+REDq[1][2]+REDq[2][2]+REDq[3][2];
      float s3 = REDq[0][3]+REDq[1][3]+REDq[2][3]+REDq[3][3];
      float B0 = REDp[0][2]+REDp[1][2]+REDp[2][2]+REDp[3][2] + sbb0;
      float B1 = REDp[0][3]+REDp[1][3]+REDp[2][3]+REDp[3][3] + sbb1;
      float B2 = REDp[0][4]+REDp[1][4]+REDp[2][4]+REDp[3][4] + sbb2;
      float B3 = REDp[0][5]+REDp[1][5]+REDp[2][5]+REDp[3][5] + sbb3;
      float4 o;
      o.x = s0 + sbp0 + B0;
      o.y = s1 + sbp1 + B1;
      o.z = tanh_(s2 + sbm0 + B2);
      o.w = tanh_(s3 + sbm1 + B3);
      *(float4*)(yo + (size_t)s * 4) = o;
    }
    xp += 6;
  }
}

extern "C" void kernel_launch(void* const* d_in, const int* in_sizes, int n_in,
                              void* d_out, int out_size, void* d_ws, size_t ws_size,
                              hipStream_t stream)
{
  const float* x        = (const float*)d_in[0];
  const float* w_ih     = (const float*)d_in[1];
  const float* w_hh     = (const float*)d_in[2];
  const float* b_ih     = (const float*)d_in[3];
  const float* b_hh     = (const float*)d_in[4];
  const float* w_gain   = (const float*)d_in[5];
  const float* b_gain   = (const float*)d_in[6];
  const float* w_bias   = (const float*)d_in[7];
  const float* b_bias   = (const float*)d_in[8];
  const float* w_reflex = (const float*)d_in[9];
  const float* b_reflex = (const float*)d_in[10];
  const float* w_policy = (const float*)d_in[11];
  const float* b_policy = (const float*)d_in[12];
  const float* w_motor  = (const float*)d_in[13];
  const float* b_motor  = (const float*)d_in[14];

  float* y_out  = (float*)d_out;
  float* router = (float*)d_out + (size_t)Bn * Sn * 4;

  bio_rnn<<<dim3(Bn), dim3(NT), 0, stream>>>(
      x, w_ih, w_hh, b_ih, b_hh, w_gain, b_gain, w_bias, b_bias,
      w_reflex, b_reflex, w_policy, b_policy, w_motor, b_motor,
      y_out, router);
}

// Round 3
// 6341.190 us; speedup vs baseline: 1.0551x; 1.0551x over previous
//
#include <hip/hip_runtime.h>
#include <cstdint>
#include <cstddef>

#define Hn 256
#define Sn 2048
#define Bn 128
#define NT 1024

typedef _Float16 half2_t __attribute__((ext_vector_type(2)));

__device__ __forceinline__ float fdot2_(half2_t a, half2_t b, float c){
#if __has_builtin(__builtin_amdgcn_fdot2)
  return __builtin_amdgcn_fdot2(a, b, c, false);
#else
  float d;
  asm volatile("v_dot2_f32_f16 %0, %1, %2, %3" : "=v"(d) : "v"(a), "v"(b), "v"(c));
  return d;
#endif
}

// sum over the 4 lanes of each quad via DPP quad_perm (pure VALU)
__device__ __forceinline__ float qsum_(float v){
  int x = __builtin_bit_cast(int, v);
  int y = __builtin_amdgcn_mov_dpp(x, 0xB1, 0xF, 0xF, true);   // [1,0,3,2]
  v += __builtin_bit_cast(float, y);
  x = __builtin_bit_cast(int, v);
  y = __builtin_amdgcn_mov_dpp(x, 0x4E, 0xF, 0xF, true);       // [2,3,0,1]
  return v + __builtin_bit_cast(float, y);
}

__device__ __forceinline__ float rfl_(float v){
  return __builtin_bit_cast(float, __builtin_amdgcn_readfirstlane(__builtin_bit_cast(int, v)));
}

__device__ __forceinline__ float sigmoid_(float v){ return 1.0f/(1.0f+__expf(-v)); }
__device__ __forceinline__ float tanh_(float v){
  float e = __expf(-2.0f*__builtin_fabsf(v));
  float r = (1.0f-e)/(1.0f+e);
  return __builtin_copysignf(r, v);
}

// One workgroup (1024 thr, 1 block/CU) per batch element. Thread t:
// j = t>>2 (h-index), kq = t&3 (K-quarter). Owns K-chunk [64kq,64kq+64) of
// w_hh rows {j, j+256, j+512}: 96 f16-pair VGPRs, register-resident under the
// 128-VGPR cap from __launch_bounds__(1024, 1).
__global__ void __launch_bounds__(NT, 1)
bio_rnn(const float* __restrict__ x,
        const float* __restrict__ w_ih, const float* __restrict__ w_hh,
        const float* __restrict__ b_ih, const float* __restrict__ b_hh,
        const float* __restrict__ w_gain, const float* __restrict__ b_gain,
        const float* __restrict__ w_bias, const float* __restrict__ b_bias,
        const float* __restrict__ w_reflex, const float* __restrict__ b_reflex,
        const float* __restrict__ w_policy, const float* __restrict__ b_policy,
        const float* __restrict__ w_motor, const float* __restrict__ b_motor,
        float* __restrict__ y_out, float* __restrict__ router)
{
  const int b  = blockIdx.x;
  const int t  = threadIdx.x;
  const int kq = t & 3;
  const int j  = t >> 2;

  // h packed f16; 4 chunks of 64 halves, 160 B stride -> quad reads hit 4
  // distinct banks, 16-lane same-address broadcast each (conflict-free).
  __shared__ __align__(16) unsigned char hraw[4*160];
  __shared__ float PRE[4][Hn];          // pre-activations: r, z, gh_n, gi_n
  __shared__ float REDp[4][8];          // gain/bias head wave-partials
  __shared__ float REDq[4][4];          // policy/motor head wave-partials
  __shared__ float HW[13][Hn];          // head weights
  __shared__ float SB[10];              // block-uniform head biases

  // ---- register-cache w_hh: 3 rows x 32 half2 = 96 VGPRs ----
  half2_t w0[32], w1[32], w2[32];
  {
    const float* p0 = w_hh + (size_t)(j       )*Hn + kq*64;
    const float* p1 = w_hh + (size_t)(j +   Hn)*Hn + kq*64;
    const float* p2 = w_hh + (size_t)(j + 2*Hn)*Hn + kq*64;
    #pragma unroll
    for (int m = 0; m < 32; m++){
      half2_t a; a.x=(_Float16)p0[2*m]; a.y=(_Float16)p0[2*m+1]; w0[m]=a;
      half2_t c; c.x=(_Float16)p1[2*m]; c.y=(_Float16)p1[2*m+1]; w1[m]=c;
      half2_t d; d.x=(_Float16)p2[2*m]; d.y=(_Float16)p2[2*m+1]; w2[m]=d;
    }
  }
  // gi fold: kq 0/1/2 handle x-dims {2kq,2kq+1}; kq==3 carries the biases.
  half2_t wi0, wi1, wi2; float bd0, bd1, bd2, bd3;
  {
    half2_t z; z.x=(_Float16)0.f; z.y=(_Float16)0.f;
    wi0=z; wi1=z; wi2=z; bd0=bd1=bd2=bd3=0.f;
    if (kq < 3){
      wi0.x=(_Float16)w_ih[(size_t)(j       )*6+2*kq]; wi0.y=(_Float16)w_ih[(size_t)(j       )*6+2*kq+1];
      wi1.x=(_Float16)w_ih[(size_t)(j +   Hn)*6+2*kq]; wi1.y=(_Float16)w_ih[(size_t)(j +   Hn)*6+2*kq+1];
      wi2.x=(_Float16)w_ih[(size_t)(j + 2*Hn)*6+2*kq]; wi2.y=(_Float16)w_ih[(size_t)(j + 2*Hn)*6+2*kq+1];
    } else {
      bd0 = b_ih[j]      + b_hh[j];
      bd1 = b_ih[j+Hn]   + b_hh[j+Hn];
      bd2 = b_hh[j+2*Hn];                 // gh_n bias (inside r*gh_n)
      bd3 = b_ih[j+2*Hn];                 // gi_n bias
    }
  }
  if (t < Hn){
    HW[0][t] = w_gain[t];        HW[1][t]  = w_gain[Hn + t];
    HW[2][t] = w_bias[t];        HW[3][t]  = w_bias[Hn + t];
    HW[4][t] = w_bias[2*Hn + t]; HW[5][t]  = w_bias[3*Hn + t];
    HW[6][t] = w_reflex[2*t];    HW[7][t]  = w_reflex[2*t + 1];
    HW[8][t] = b_reflex[t];
    HW[9][t] = w_policy[t];      HW[10][t] = w_policy[Hn + t];
    HW[11][t] = w_motor[t];      HW[12][t] = w_motor[Hn + t];
  }
  if (t < 160) ((unsigned int*)hraw)[t] = 0u;
  if (t == 0){
    SB[0]=b_gain[0]; SB[1]=b_gain[1];
    SB[2]=b_bias[0]; SB[3]=b_bias[1]; SB[4]=b_bias[2]; SB[5]=b_bias[3];
    SB[6]=b_policy[0]; SB[7]=b_policy[1]; SB[8]=b_motor[0]; SB[9]=b_motor[1];
  }
  float hprev = 0.f;
  __syncthreads();

  const float* xp   = x      + (size_t)b * Sn * 6;
  float* rbase      = router + (size_t)b * Sn * Hn;
  const uint4* hc   = (const uint4*)(hraw + kq*160);

  for (int s = 0; s < Sn; s++){
    // block-uniform x: force into SGPRs
    const float x0=rfl_(xp[0]), x1=rfl_(xp[1]), x2=rfl_(xp[2]);
    const float x3=rfl_(xp[3]), x4=rfl_(xp[4]), x5=rfl_(xp[5]);
    // this thread's x-pair (kq==3: wi operands are zero, value irrelevant)
    float xa = (kq==0)?x0:((kq==1)?x2:x4);
    float xb = (kq==0)?x1:((kq==1)?x3:x5);
    half2_t xpk; xpk.x=(_Float16)xa; xpk.y=(_Float16)xb;

    float a0=bd0, a1=bd1, a2=bd2, a3=bd3;
    a0 = fdot2_(wi0, xpk, a0);      // gi fold for r row
    a1 = fdot2_(wi1, xpk, a1);      // gi fold for z row
    a3 = fdot2_(wi2, xpk, a3);      // gi_n partial (kept separate from gh_n)

    #pragma unroll
    for (int i = 0; i < 8; i++){
      uint4 hv = hc[i];             // ds_read_b128 broadcast
      half2_t h0 = __builtin_bit_cast(half2_t, hv.x);
      half2_t h1 = __builtin_bit_cast(half2_t, hv.y);
      half2_t h2 = __builtin_bit_cast(half2_t, hv.z);
      half2_t h3 = __builtin_bit_cast(half2_t, hv.w);
      a0=fdot2_(w0[4*i+0],h0,a0); a1=fdot2_(w1[4*i+0],h0,a1); a2=fdot2_(w2[4*i+0],h0,a2);
      a0=fdot2_(w0[4*i+1],h1,a0); a1=fdot2_(w1[4*i+1],h1,a1); a2=fdot2_(w2[4*i+1],h1,a2);
      a0=fdot2_(w0[4*i+2],h2,a0); a1=fdot2_(w1[4*i+2],h2,a1); a2=fdot2_(w2[4*i+2],h2,a2);
      a0=fdot2_(w0[4*i+3],h3,a0); a1=fdot2_(w1[4*i+3],h3,a1); a2=fdot2_(w2[4*i+3],h3,a2);
    }
    // combine the 4 K-partials within each quad (pure VALU)
    a0 = qsum_(a0); a1 = qsum_(a1); a2 = qsum_(a2); a3 = qsum_(a3);
    if (kq == 0){ PRE[0][j]=a0; PRE[1][j]=a1; PRE[2][j]=a2; PRE[3][j]=a3; }
    __syncthreads();                                        // W1

    if (t < Hn){
      float pr = PRE[0][t], pz = PRE[1][t], pg = PRE[2][t], pn = PRE[3][t];
      float r = sigmoid_(pr);
      float z = sigmoid_(pz);
      float n = tanh_(pn + r*pg);
      float h = (1.f - z)*n + z*hprev;
      hprev = h;
      *(_Float16*)(hraw + (t>>6)*160 + (t&63)*2) = (_Float16)h;
      rbase[(size_t)s*Hn + t] = h;                          // router_activity
      float p0=h*HW[0][t], p1=h*HW[1][t], p2=h*HW[2][t];
      float p3=h*HW[3][t], p4=h*HW[4][t], p5=h*HW[5][t];
      #pragma unroll
      for (int off = 32; off >= 1; off >>= 1){
        p0 += __shfl_xor(p0, off); p1 += __shfl_xor(p1, off); p2 += __shfl_xor(p2, off);
        p3 += __shfl_xor(p3, off); p4 += __shfl_xor(p4, off); p5 += __shfl_xor(p5, off);
      }
      if ((t & 63) == 0){
        const int wv = t >> 6;
        REDp[wv][0]=p0; REDp[wv][1]=p1; REDp[wv][2]=p2;
        REDp[wv][3]=p3; REDp[wv][4]=p4; REDp[wv][5]=p5;
      }
    }
    __syncthreads();                                        // W2
    if (t < Hn){
      float g0 = REDp[0][0]+REDp[1][0]+REDp[2][0]+REDp[3][0] + SB[0];
      float g1 = REDp[0][1]+REDp[1][1]+REDp[2][1]+REDp[3][1] + SB[1];
      g0 = sigmoid_(g0); g1 = sigmoid_(g1);
      float f = (x0*g0)*HW[6][t] + (x1*g1)*HW[7][t] + HW[8][t];
      f = fmaxf(f, 0.f);                                    // feat
      float q0=f*HW[9][t], q1=f*HW[10][t], q2=f*HW[11][t], q3=f*HW[12][t];
      #pragma unroll
      for (int off = 32; off >= 1; off >>= 1){
        q0 += __shfl_xor(q0, off); q1 += __shfl_xor(q1, off);
        q2 += __shfl_xor(q2, off); q3 += __shfl_xor(q3, off);
      }
      if ((t & 63) == 0){
        const int wv = t >> 6;
        REDq[wv][0]=q0; REDq[wv][1]=q1; REDq[wv][2]=q2; REDq[wv][3]=q3;
      }
    }
    __syncthreads();                                        // W3
    if (t == 0){
      float s0 = REDq[0][0]+REDq[1][0]+REDq[2][0]+REDq[3][0];
      float s1 = REDq[0][1]+REDq[1][1]+REDq[2][1]+REDq[3][1];
      float s2 = REDq[0][2]+REDq[1][2]+REDq[2][2]+REDq[3][2];
      float s3 = REDq[0][3]+REDq[1][3]+REDq[2][3]+REDq[3][3];
      float B0 = REDp[0][2]+REDp[1][2]+REDp[2][2]+REDp[3][2] + SB[2];
      float B1 = REDp[0][3]+REDp[1][3]+REDp[2][3]+REDp[3][3] + SB[3];
      float B2 = REDp[0][4]+REDp[1][4]+REDp[2][4]+REDp[3][4] + SB[4];
      float B3 = REDp[0][5]+REDp[1][5]+REDp[2][5]+REDp[3][5] + SB[5];
      float4 o;
      o.x = s0 + SB[6] + B0;
      o.y = s1 + SB[7] + B1;
      o.z = tanh_(s2 + SB[8] + B2);
      o.w = tanh_(s3 + SB[9] + B3);
      *(float4*)(y_out + (size_t)b * Sn * 4 + (size_t)s * 4) = o;
    }
    xp += 6;
  }
}

extern "C" void kernel_launch(void* const* d_in, const int* in_sizes, int n_in,
                              void* d_out, int out_size, void* d_ws, size_t ws_size,
                              hipStream_t stream)
{
  const float* x        = (const float*)d_in[0];
  const float* w_ih     = (const float*)d_in[1];
  const float* w_hh     = (const float*)d_in[2];
  const float* b_ih     = (const float*)d_in[3];
  const float* b_hh     = (const float*)d_in[4];
  const float* w_gain   = (const float*)d_in[5];
  const float* b_gain   = (const float*)d_in[6];
  const float* w_bias   = (const float*)d_in[7];
  const float* b_bias   = (const float*)d_in[8];
  const float* w_reflex = (const float*)d_in[9];
  const float* b_reflex = (const float*)d_in[10];
  const float* w_policy = (const float*)d_in[11];
  const float* b_policy = (const float*)d_in[12];
  const float* w_motor  = (const float*)d_in[13];
  const float* b_motor  = (const float*)d_in[14];

  float* y_out  = (float*)d_out;
  float* router = (float*)d_out + (size_t)Bn * Sn * 4;

  bio_rnn<<<dim3(Bn), dim3(NT), 0, stream>>>(
      x, w_ih, w_hh, b_ih, b_hh, w_gain, b_gain, w_bias, b_bias,
      w_reflex, b_reflex, w_policy, b_policy, w_motor, b_motor,
      y_out, router);
}

// Round 4
// 6333.254 us; speedup vs baseline: 1.0564x; 1.0013x over previous
//
#include <hip/hip_runtime.h>
#include <cstdint>
#include <cstddef>

#define Hn 256
#define Sn 2048
#define Bn 128
#define NT 1024

typedef _Float16 half2_t __attribute__((ext_vector_type(2)));

__device__ __forceinline__ float fdot2_(half2_t a, half2_t b, float c){
#if __has_builtin(__builtin_amdgcn_fdot2)
  return __builtin_amdgcn_fdot2(a, b, c, false);
#else
  float d;
  asm volatile("v_dot2_f32_f16 %0, %1, %2, %3" : "=v"(d) : "v"(a), "v"(b), "v"(c));
  return d;
#endif
}

// sum over the 4 lanes of each quad via DPP quad_perm (pure VALU)
__device__ __forceinline__ float qsum_(float v){
  int x = __builtin_bit_cast(int, v);
  int y = __builtin_amdgcn_mov_dpp(x, 0xB1, 0xF, 0xF, true);   // [1,0,3,2]
  v += __builtin_bit_cast(float, y);
  x = __builtin_bit_cast(int, v);
  y = __builtin_amdgcn_mov_dpp(x, 0x4E, 0xF, 0xF, true);       // [2,3,0,1]
  return v + __builtin_bit_cast(float, y);
}

__device__ __forceinline__ float rfl_(float v){
  return __builtin_bit_cast(float, __builtin_amdgcn_readfirstlane(__builtin_bit_cast(int, v)));
}

__device__ __forceinline__ float sigmoid_(float v){ return 1.0f/(1.0f+__expf(-v)); }
__device__ __forceinline__ float tanh_(float v){
  float e = __expf(-2.0f*__builtin_fabsf(v));
  float r = (1.0f-e)/(1.0f+e);
  return __builtin_copysignf(r, v);
}

// One workgroup (1024 thr) per batch element. Thread t: j = t>>2 (h-index),
// kq = t&3 (K-quarter). Owns K-chunk [64kq,64kq+64) of w_hh rows
// {j, j+256, j+512}: 96 f16-pair VGPRs.
// amdgpu_waves_per_eu(4,4): pin allocator to 4 waves/SIMD -> 128-VGPR cap,
// weights register-resident (launch_bounds alone left the backend at 8
// waves/EU -> 64 VGPRs -> full weight spill; rounds 1-3 evidence).
__global__ void
__attribute__((amdgpu_flat_work_group_size(NT, NT), amdgpu_waves_per_eu(4, 4)))
bio_rnn(const float* __restrict__ x,
        const float* __restrict__ w_ih, const float* __restrict__ w_hh,
        const float* __restrict__ b_ih, const float* __restrict__ b_hh,
        const float* __restrict__ w_gain, const float* __restrict__ b_gain,
        const float* __restrict__ w_bias, const float* __restrict__ b_bias,
        const float* __restrict__ w_reflex, const float* __restrict__ b_reflex,
        const float* __restrict__ w_policy, const float* __restrict__ b_policy,
        const float* __restrict__ w_motor, const float* __restrict__ b_motor,
        float* __restrict__ y_out, float* __restrict__ router)
{
  const int b  = blockIdx.x;
  const int t  = threadIdx.x;
  const int kq = t & 3;
  const int j  = t >> 2;

  // h packed f16; 4 chunks of 64 halves, 160 B stride -> quad reads hit 4
  // distinct banks, 16-lane same-address broadcast each (conflict-free).
  __shared__ __align__(16) unsigned char hraw[4*160];
  __shared__ float PRE[4][Hn];          // pre-activations: r, z, gh_n, gi_n
  __shared__ float REDp[4][8];          // gain/bias head wave-partials
  __shared__ float REDq[4][4];          // policy/motor head wave-partials
  __shared__ float HW[13][Hn];          // head weights
  __shared__ float SB[10];              // block-uniform head biases

  // ---- register-cache w_hh: 3 rows x 32 half2 = 96 VGPRs ----
  half2_t w0[32], w1[32], w2[32];
  {
    const float* p0 = w_hh + (size_t)(j       )*Hn + kq*64;
    const float* p1 = w_hh + (size_t)(j +   Hn)*Hn + kq*64;
    const float* p2 = w_hh + (size_t)(j + 2*Hn)*Hn + kq*64;
    #pragma unroll
    for (int m = 0; m < 32; m++){
      half2_t a; a.x=(_Float16)p0[2*m]; a.y=(_Float16)p0[2*m+1]; w0[m]=a;
      half2_t c; c.x=(_Float16)p1[2*m]; c.y=(_Float16)p1[2*m+1]; w1[m]=c;
      half2_t d; d.x=(_Float16)p2[2*m]; d.y=(_Float16)p2[2*m+1]; w2[m]=d;
    }
  }
  // gi fold: kq 0/1/2 handle x-dims {2kq,2kq+1}; kq==3 carries the biases.
  half2_t wi0, wi1, wi2; float bd0, bd1, bd2, bd3;
  {
    half2_t z; z.x=(_Float16)0.f; z.y=(_Float16)0.f;
    wi0=z; wi1=z; wi2=z; bd0=bd1=bd2=bd3=0.f;
    if (kq < 3){
      wi0.x=(_Float16)w_ih[(size_t)(j       )*6+2*kq]; wi0.y=(_Float16)w_ih[(size_t)(j       )*6+2*kq+1];
      wi1.x=(_Float16)w_ih[(size_t)(j +   Hn)*6+2*kq]; wi1.y=(_Float16)w_ih[(size_t)(j +   Hn)*6+2*kq+1];
      wi2.x=(_Float16)w_ih[(size_t)(j + 2*Hn)*6+2*kq]; wi2.y=(_Float16)w_ih[(size_t)(j + 2*Hn)*6+2*kq+1];
    } else {
      bd0 = b_ih[j]      + b_hh[j];
      bd1 = b_ih[j+Hn]   + b_hh[j+Hn];
      bd2 = b_hh[j+2*Hn];                 // gh_n bias (inside r*gh_n)
      bd3 = b_ih[j+2*Hn];                 // gi_n bias
    }
  }
  if (t < Hn){
    HW[0][t] = w_gain[t];        HW[1][t]  = w_gain[Hn + t];
    HW[2][t] = w_bias[t];        HW[3][t]  = w_bias[Hn + t];
    HW[4][t] = w_bias[2*Hn + t]; HW[5][t]  = w_bias[3*Hn + t];
    HW[6][t] = w_reflex[2*t];    HW[7][t]  = w_reflex[2*t + 1];
    HW[8][t] = b_reflex[t];
    HW[9][t] = w_policy[t];      HW[10][t] = w_policy[Hn + t];
    HW[11][t] = w_motor[t];      HW[12][t] = w_motor[Hn + t];
  }
  if (t < 160) ((unsigned int*)hraw)[t] = 0u;
  if (t == 0){
    SB[0]=b_gain[0]; SB[1]=b_gain[1];
    SB[2]=b_bias[0]; SB[3]=b_bias[1]; SB[4]=b_bias[2]; SB[5]=b_bias[3];
    SB[6]=b_policy[0]; SB[7]=b_policy[1]; SB[8]=b_motor[0]; SB[9]=b_motor[1];
  }
  float hprev = 0.f;
  __syncthreads();

  const float* xp   = x      + (size_t)b * Sn * 6;
  float* rbase      = router + (size_t)b * Sn * Hn;
  const uint4* hc   = (const uint4*)(hraw + kq*160);

  for (int s = 0; s < Sn; s++){
    // block-uniform x: force into SGPRs
    const float x0=rfl_(xp[0]), x1=rfl_(xp[1]), x2=rfl_(xp[2]);
    const float x3=rfl_(xp[3]), x4=rfl_(xp[4]), x5=rfl_(xp[5]);
    // this thread's x-pair (kq==3: wi operands are zero, value irrelevant)
    float xa = (kq==0)?x0:((kq==1)?x2:x4);
    float xb = (kq==0)?x1:((kq==1)?x3:x5);
    half2_t xpk; xpk.x=(_Float16)xa; xpk.y=(_Float16)xb;

    float a0=bd0, a1=bd1, a2=bd2, a3=bd3;
    a0 = fdot2_(wi0, xpk, a0);      // gi fold for r row
    a1 = fdot2_(wi1, xpk, a1);      // gi fold for z row
    a3 = fdot2_(wi2, xpk, a3);      // gi_n partial (kept separate from gh_n)

    #pragma unroll
    for (int i = 0; i < 8; i++){
      uint4 hv = hc[i];             // ds_read_b128 broadcast
      half2_t h0 = __builtin_bit_cast(half2_t, hv.x);
      half2_t h1 = __builtin_bit_cast(half2_t, hv.y);
      half2_t h2 = __builtin_bit_cast(half2_t, hv.z);
      half2_t h3 = __builtin_bit_cast(half2_t, hv.w);
      a0=fdot2_(w0[4*i+0],h0,a0); a1=fdot2_(w1[4*i+0],h0,a1); a2=fdot2_(w2[4*i+0],h0,a2);
      a0=fdot2_(w0[4*i+1],h1,a0); a1=fdot2_(w1[4*i+1],h1,a1); a2=fdot2_(w2[4*i+1],h1,a2);
      a0=fdot2_(w0[4*i+2],h2,a0); a1=fdot2_(w1[4*i+2],h2,a1); a2=fdot2_(w2[4*i+2],h2,a2);
      a0=fdot2_(w0[4*i+3],h3,a0); a1=fdot2_(w1[4*i+3],h3,a1); a2=fdot2_(w2[4*i+3],h3,a2);
    }
    // combine the 4 K-partials within each quad (pure VALU)
    a0 = qsum_(a0); a1 = qsum_(a1); a2 = qsum_(a2); a3 = qsum_(a3);
    if (kq == 0){ PRE[0][j]=a0; PRE[1][j]=a1; PRE[2][j]=a2; PRE[3][j]=a3; }
    __syncthreads();                                        // W1

    if (t < Hn){
      float pr = PRE[0][t], pz = PRE[1][t], pg = PRE[2][t], pn = PRE[3][t];
      float r = sigmoid_(pr);
      float z = sigmoid_(pz);
      float n = tanh_(pn + r*pg);
      float h = (1.f - z)*n + z*hprev;
      hprev = h;
      *(_Float16*)(hraw + (t>>6)*160 + (t&63)*2) = (_Float16)h;
      rbase[(size_t)s*Hn + t] = h;                          // router_activity
      float p0=h*HW[0][t], p1=h*HW[1][t], p2=h*HW[2][t];
      float p3=h*HW[3][t], p4=h*HW[4][t], p5=h*HW[5][t];
      #pragma unroll
      for (int off = 32; off >= 1; off >>= 1){
        p0 += __shfl_xor(p0, off); p1 += __shfl_xor(p1, off); p2 += __shfl_xor(p2, off);
        p3 += __shfl_xor(p3, off); p4 += __shfl_xor(p4, off); p5 += __shfl_xor(p5, off);
      }
      if ((t & 63) == 0){
        const int wv = t >> 6;
        REDp[wv][0]=p0; REDp[wv][1]=p1; REDp[wv][2]=p2;
        REDp[wv][3]=p3; REDp[wv][4]=p4; REDp[wv][5]=p5;
      }
    }
    __syncthreads();                                        // W2
    if (t < Hn){
      float g0 = REDp[0][0]+REDp[1][0]+REDp[2][0]+REDp[3][0] + SB[0];
      float g1 = REDp[0][1]+REDp[1][1]+REDp[2][1]+REDp[3][1] + SB[1];
      g0 = sigmoid_(g0); g1 = sigmoid_(g1);
      float f = (x0*g0)*HW[6][t] + (x1*g1)*HW[7][t] + HW[8][t];
      f = fmaxf(f, 0.f);                                    // feat
      float q0=f*HW[9][t], q1=f*HW[10][t], q2=f*HW[11][t], q3=f*HW[12][t];
      #pragma unroll
      for (int off = 32; off >= 1; off >>= 1){
        q0 += __shfl_xor(q0, off); q1 += __shfl_xor(q1, off);
        q2 += __shfl_xor(q2, off); q3 += __shfl_xor(q3, off);
      }
      if ((t & 63) == 0){
        const int wv = t >> 6;
        REDq[wv][0]=q0; REDq[wv][1]=q1; REDq[wv][2]=q2; REDq[wv][3]=q3;
      }
    }
    __syncthreads();                                        // W3
    if (t == 0){
      float s0 = REDq[0][0]+REDq[1][0]+REDq[2][0]+REDq[3][0];
      float s1 = REDq[0][1]+REDq[1][1]+REDq[2][1]+REDq[3][1];
      float s2 = REDq[0][2]+REDq[1][2]+REDq[2][2]+REDq[3][2];
      float s3 = REDq[0][3]+REDq[1][3]+REDq[2][3]+REDq[3][3];
      float B0 = REDp[0][2]+REDp[1][2]+REDp[2][2]+REDp[3][2] + SB[2];
      float B1 = REDp[0][3]+REDp[1][3]+REDp[2][3]+REDp[3][3] + SB[3];
      float B2 = REDp[0][4]+REDp[1][4]+REDp[2][4]+REDp[3][4] + SB[4];
      float B3 = REDp[0][5]+REDp[1][5]+REDp[2][5]+REDp[3][5] + SB[5];
      float4 o;
      o.x = s0 + SB[6] + B0;
      o.y = s1 + SB[7] + B1;
      o.z = tanh_(s2 + SB[8] + B2);
      o.w = tanh_(s3 + SB[9] + B3);
      *(float4*)(y_out + (size_t)b * Sn * 4 + (size_t)s * 4) = o;
    }
    xp += 6;
  }
}

extern "C" void kernel_launch(void* const* d_in, const int* in_sizes, int n_in,
                              void* d_out, int out_size, void* d_ws, size_t ws_size,
                              hipStream_t stream)
{
  const float* x        = (const float*)d_in[0];
  const float* w_ih     = (const float*)d_in[1];
  const float* w_hh     = (const float*)d_in[2];
  const float* b_ih     = (const float*)d_in[3];
  const float* b_hh     = (const float*)d_in[4];
  const float* w_gain   = (const float*)d_in[5];
  const float* b_gain   = (const float*)d_in[6];
  const float* w_bias   = (const float*)d_in[7];
  const float* b_bias   = (const float*)d_in[8];
  const float* w_reflex = (const float*)d_in[9];
  const float* b_reflex = (const float*)d_in[10];
  const float* w_policy = (const float*)d_in[11];
  const float* b_policy = (const float*)d_in[12];
  const float* w_motor  = (const float*)d_in[13];
  const float* b_motor  = (const float*)d_in[14];

  float* y_out  = (float*)d_out;
  float* router = (float*)d_out + (size_t)Bn * Sn * 4;

  bio_rnn<<<dim3(Bn), dim3(NT), 0, stream>>>(
      x, w_ih, w_hh, b_ih, b_hh, w_gain, b_gain, w_bias, b_bias,
      w_reflex, b_reflex, w_policy, b_policy, w_motor, b_motor,
      y_out, router);
}